// Round 23
// baseline (196.304 us; speedup 1.0000x reference)
//
#include <hip/hip_runtime.h>
#include <hip/hip_bf16.h>
#include <stdint.h>

using u16 = unsigned short;
using u32 = unsigned int;
using u8  = unsigned char;

#define NB 64
#define TT 128
#define DK 768
#define MC 30

typedef float f32x16 __attribute__((ext_vector_type(16)));
typedef __bf16 bf16x8 __attribute__((ext_vector_type(8)));
typedef long long ll;
typedef __attribute__((ext_vector_type(2))) ll ll2;
#if __has_builtin(__builtin_amdgcn_mfma_scale_f32_32x32x64_f8f6f4)
#define HAVE_MXFP8 1
typedef int i32x8 __attribute__((ext_vector_type(8)));
#endif
#if __has_builtin(__builtin_amdgcn_global_load_lds)
#define HAVE_GLDS 1
#endif

__device__ inline void unpack2(u32 u, float& lo, float& hi){
  union{u32 i; float f;} a, b; a.i = u << 16; b.i = u & 0xFFFF0000u; lo = a.f; hi = b.f;
}
__device__ inline u16 f2bf(float f){
  union{u32 i; float f;} v; v.f = f;
  u32 r = v.i + 0x7FFFu + ((v.i >> 16) & 1u);
  return (u16)(r >> 16);
}
__device__ inline u32 pack2bf(float a, float b){ return (u32)f2bf(a) | ((u32)f2bf(b) << 16); }

// ---------------- fp8 e4m3fn pack/unpack helpers ----------------
#if __has_builtin(__builtin_amdgcn_cvt_pk_fp8_f32)
template<bool HIW>
__device__ inline u32 pk_fp8(float a, float b, u32 old){
  return (u32)__builtin_amdgcn_cvt_pk_fp8_f32(a, b, (int)old, HIW);
}
#else
__device__ inline u8 f2fp8_1(float f){
  union{float f; u32 u;} v; v.f = f;
  u32 s = (v.u >> 24) & 0x80u;
  u32 abs = v.u & 0x7fffffffu;
  if (abs < 0x3c800000u){
    float sc = fabsf(f) * 512.0f;
    int m = (int)rintf(sc);
    return (u8)(s | (u32)m);
  }
  u32 e8 = abs >> 23; u32 mant = abs & 0x7fffffu;
  u32 m3 = mant >> 20; u32 rest = mant & 0xfffffu;
  u32 rb = (rest > 0x80000u) || (rest == 0x80000u && (m3 & 1u));
  m3 += rb;
  u32 E = e8 - 120u;
  if (m3 == 8u){ m3 = 0u; E += 1u; }
  if (E >= 16u || (E == 15u && m3 == 7u)) return (u8)(s | 0x7Eu);
  return (u8)(s | (E << 3) | m3);
}
template<bool HIW>
__device__ inline u32 pk_fp8(float a, float b, u32 old){
  u32 w = (u32)f2fp8_1(a) | ((u32)f2fp8_1(b) << 8);
  return HIW ? ((old & 0x0000FFFFu) | (w << 16)) : ((old & 0xFFFF0000u) | w);
}
#endif

#if __has_builtin(__builtin_amdgcn_cvt_pk_f32_fp8)
__device__ inline void upk_fp8x4(u32 w, float* x){
  auto a0 = __builtin_amdgcn_cvt_pk_f32_fp8((int)w, false);
  auto a1 = __builtin_amdgcn_cvt_pk_f32_fp8((int)w, true);
  x[0] = a0[0]; x[1] = a0[1]; x[2] = a1[0]; x[3] = a1[1];
}
#else
__device__ inline float fp8_1(u32 byte){
  u32 s = (byte & 0x80u) << 24;
  u32 E = (byte >> 3) & 15u, M = byte & 7u;
  union{u32 u; float f;} v;
  if (E == 0){ v.f = (float)M * (1.0f/512.0f); v.u |= s; }
  else v.u = s | ((E + 120u) << 23) | (M << 20);
  return v.f;
}
__device__ inline void upk_fp8x4(u32 w, float* x){
  x[0] = fp8_1(w & 255u); x[1] = fp8_1((w >> 8) & 255u);
  x[2] = fp8_1((w >> 16) & 255u); x[3] = fp8_1(w >> 24);
}
#endif

// ic PERMUTATION (applied identically to w2p, c2in, act2, conv3 weights):
// channel c = 8q + 4h + j  lives at byte p = h*16 + q*4 + j   (q,j in 0..3, h in 0..1)

// ---------------- kernel 1: row norms + bf16 conversion (PRE-SWIZZLED output)
//                  + fused weight prep (blocks >= 4096) + dis zero-init ----------------
__global__ __launch_bounds__(256) void row_norms_k(const float* __restrict__ q, const float* __restrict__ k,
    float* __restrict__ qq, float* __restrict__ kk,
    u16* __restrict__ qb16, u16* __restrict__ kb16,
    const float* __restrict__ w2, const float* __restrict__ w1,
    u8* __restrict__ w2p, u16* __restrict__ w1c, float* __restrict__ out_dis){
  if (blockIdx.x >= 4096){
    int bidx = blockIdx.x - 4096;
    if (bidx < 25){
      int tap = bidx;
      int i = threadIdx.x;
      int oc = i >> 3, qd = i & 7;
      int ic0 = 8*(qd & 3) + 4*(qd >> 2);   // permuted: byte qd*4 holds channels ic0..ic0+3
      float v[4];
      #pragma unroll
      for (int j = 0; j < 4; ++j)
        v[j] = (oc < MC && ic0 + j < MC) ? w2[(oc*MC + ic0 + j)*25 + tap] : 0.f;
      u32 w = pk_fp8<false>(v[0], v[1], 0u);
      w = pk_fp8<true>(v[2], v[3], w);
      int lo = ((oc << 5) + (qd << 2)) ^ ((oc & 7) << 4);
      *(u32*)(w2p + tap*1024 + lo) = w;
    } else if (bidx == 25){
      for (int i = threadIdx.x; i < 2560; i += 256){
        int dy = i >> 9; int rem = i & 511; int oc = rem >> 4; int kx = rem & 15;
        int dx = kx >> 1, c = kx & 1;
        float v = (oc < MC && dx < 5) ? w1[(oc*2 + c)*25 + dy*5 + dx] : 0.f;
        int byteoff = dy*1024 + (((oc<<5) + (kx<<1)) ^ ((oc&7)<<4));
        *(u16*)((char*)w1c + byteoff) = f2bf(v);
      }
    } else {
      if (threadIdx.x < NB) out_dis[threadIdx.x] = 0.f;
    }
    return;
  }
  int wave = blockIdx.x * 4 + (threadIdx.x >> 6);
  int lane = threadIdx.x & 63;
  const float* src; float* dst; u16* bdst; int row;
  if (wave < NB * TT) { src = q; dst = qq; bdst = qb16; row = wave; }
  else                { src = k; dst = kk; bdst = kb16; row = wave - NB * TT; }
  const float4* p = (const float4*)(src + (size_t)row * DK);
  char* ob = (char*)(bdst + (size_t)row * DK);
  int key = (row & 7) << 4;
  float s = 0.f;
  {
    float4 a = p[2*lane], b2 = p[2*lane + 1];
    s += a.x*a.x + a.y*a.y + a.z*a.z + a.w*a.w;
    s += b2.x*b2.x + b2.y*b2.y + b2.z*b2.z + b2.w*b2.w;
    uint4 st;
    st.x = pack2bf(a.x, a.y);  st.y = pack2bf(a.z, a.w);
    st.z = pack2bf(b2.x, b2.y); st.w = pack2bf(b2.z, b2.w);
    *(uint4*)(ob + ((lane << 4) ^ key)) = st;
  }
  if (lane < 32){
    int g = 64 + lane;
    float4 a = p[2*g], b2 = p[2*g + 1];
    s += a.x*a.x + a.y*a.y + a.z*a.z + a.w*a.w;
    s += b2.x*b2.x + b2.y*b2.y + b2.z*b2.z + b2.w*b2.w;
    uint4 st;
    st.x = pack2bf(a.x, a.y);  st.y = pack2bf(a.z, a.w);
    st.z = pack2bf(b2.x, b2.y); st.w = pack2bf(b2.z, b2.w);
    *(uint4*)(ob + ((g << 4) ^ key)) = st;
  }
  #pragma unroll
  for (int o = 32; o; o >>= 1) s += __shfl_xor(s, o);
  if (lane == 0) dst[row] = s;
}

// ---------------- kernel 2: cdist via bf16 MFMA, async linear staging, XCD-grouped grid ----------------
__global__ __launch_bounds__(256) void cdist_mfma_k(
    const u16* __restrict__ Qb16, const u16* __restrict__ Kb16,
    const float* __restrict__ qq, const float* __restrict__ kk,
    const int* __restrict__ qlen, const int* __restrict__ klen,
    const float* __restrict__ qR, const float* __restrict__ kR,
    float* __restrict__ Dout, u32* __restrict__ inb){
  __shared__ __align__(16) char qs[32 * 1536];
  __shared__ __align__(16) char ksm[128 * 256];
  int bid = blockIdx.x;
  int b  = ((bid & 7) << 3) + (bid >> 5);
  int rt = (bid >> 3) & 3;
  int r0 = rt * 32;
  int tid = threadIdx.x;
  int lane = tid & 63, w = tid >> 6;
  int hi = lane >> 5, l31 = lane & 31;
  const char* Qg = (const char*)(Qb16 + ((size_t)b * TT + r0) * DK);
  const char* Kg = (const char*)(Kb16 + (size_t)b * TT * DK);
#ifdef HAVE_GLDS
  #pragma unroll
  for (int i = 0; i < 12; ++i){
    int gb = (i*4 + w) << 6;
    __builtin_amdgcn_global_load_lds((const u32*)(Qg + ((gb + lane) << 4)),
                                     (u32*)(qs + (gb << 4)), 16, 0, 0);
  }
#else
  for (int idx = tid; idx < 3072; idx += 256)
    *(uint4*)(qs + idx*16) = *(const uint4*)(Qg + idx*16);
#endif
  int col = w * 32 + l31;
  f32x16 acc;
  #pragma unroll
  for (int r = 0; r < 16; ++r) acc[r] = 0.f;
  for (int kc = 0; kc < DK; kc += 128){
    __syncthreads();
#ifdef HAVE_GLDS
    const char* Ks = Kg + kc*2;
    #pragma unroll
    for (int i = 0; i < 8; ++i){
      int gb = (i*4 + w) << 6;
      int g = gb + lane;
      __builtin_amdgcn_global_load_lds((const u32*)(Ks + (g >> 4)*1536 + ((g & 15) << 4)),
                                       (u32*)(ksm + (gb << 4)), 16, 0, 0);
    }
#else
    for (int idx = tid; idx < 2048; idx += 256){
      int c = idx >> 4, j = idx & 15;
      *(uint4*)(ksm + idx*16) = *(const uint4*)(Kg + c*1536 + kc*2 + j*16);
    }
#endif
    __syncthreads();
    #pragma unroll
    for (int k8 = 0; k8 < 8; ++k8){
      bf16x8 a  = *(const bf16x8*)(qs  + l31 * 1536 + (((kc + k8*16 + hi*8) * 2) ^ ((l31 & 7) << 4)));
      bf16x8 bv = *(const bf16x8*)(ksm + col * 256  + (((k8*16 + hi*8) * 2) ^ ((col & 7) << 4)));
      acc = __builtin_amdgcn_mfma_f32_32x32x16_bf16(a, bv, acc, 0, 0, 0);
    }
  }
  int ql = qlen[b], kl = klen[b];
  float kkv = kk[b * TT + col];
  float krv = kR[b * TT + col];
  bool cm = col < kl;
  #pragma unroll
  for (int r = 0; r < 16; ++r){
    int row = r0 + (r & 3) + 8 * (r >> 2) + 4 * hi;
    float qqv = qq[b * TT + row];
    float sq = qqv + kkv - 2.f * acc[r];
    float d = sqrtf(fmaxf(sq, 1e-12f));
    bool m = (row < ql) && cm;
    float dm = m ? d : 0.f;
    float pm = m ? fabsf(qR[b * TT + row] - krv) : 0.f;
    Dout[(((size_t)b * TT + row) << 7) + col] = dm;
    inb[(((size_t)b * TT + row) << 7) + col] = pack2bf(dm, pm);
  }
}

// ---------------- fused conv1+conv2 (permuted-ic contiguous stores, setprio MFMA) ----------------
#define C1_ROWW 136
#define C2_IN_ROWB 4224                 // 132 px * 32 B
#define F_INB_BYTES (16*C1_ROWW*4)      // 8704
#define F_C2_OFF F_INB_BYTES
#define F_SMEM (F_INB_BYTES + 12*C2_IN_ROWB)   // 59392

__global__ __launch_bounds__(512, 4) void conv12_mfma_k(
    const u32* __restrict__ inb, const u8* __restrict__ w2p, const u16* __restrict__ w1c,
    const float* __restrict__ b1, const float* __restrict__ b2, u8* __restrict__ act2){
  __shared__ __align__(16) char smem[F_SMEM];
  u32* ilds = (u32*)smem;
  char* c2in = smem + F_C2_OFF;
  int o  = blockIdx.x;
  int yg = ((o & 7) << 1) + (o >> 3);
  int bb = blockIdx.y;
  int y0 = yg * 8;
  int tid = threadIdx.x;
  for (int i = tid; i < 16*C1_ROWW; i += 512){
    int r = i / C1_ROWW, xi = i - r * C1_ROWW;
    int gy = y0 - 4 + r, gx = xi - 2;
    u32 v = 0;
    if ((unsigned)gy < 128u && (unsigned)gx < 128u)
      v = inb[(((size_t)bb * 128 + gy) << 7) + gx];
    ilds[r * C1_ROWW + xi] = v;
  }
  for (int i = tid; i < 96; i += 512){
    int r = i >> 3; int rem = i & 7; int ci = rem >> 1; int h = rem & 1;
    int lx = (ci < 2) ? ci : (128 + ci);
    int addr = r*C2_IN_ROWB + (((lx << 5) + (h << 4)) ^ ((lx & 7) << 4));
    *(uint4*)(c2in + addr) = make_uint4(0,0,0,0);
  }
  int lane = tid & 63, w = tid >> 6;
  int hi = lane >> 5, l31 = lane & 31;
  int aSwz = ((l31 << 5) + (hi << 4)) ^ ((l31 & 7) << 4);
  bf16x8 afr[5];
  #pragma unroll
  for (int dy = 0; dy < 5; ++dy)
    afr[dy] = *(const bf16x8*)((const char*)w1c + dy*1024 + aSwz);
  float b1v[16];
  #pragma unroll
  for (int r = 0; r < 16; ++r){
    int oc = (r & 3) + 8*(r >> 2) + 4*hi;
    b1v[r] = (oc < MC) ? b1[oc] : 0.f;
  }
  __syncthreads();
  // ---- conv1 phase
  for (int rep = 0; rep < 2; ++rep){
    if (rep == 1 && w >= 4) break;
    int idx = (rep == 0) ? w : (8 + w);
    int gy = y0 - 2 + idx;
    bool oob = (unsigned)gy >= 128u;
    #pragma unroll
    for (int t = 0; t < 4; ++t){
      int px = t*32 + l31;
      uint4 st = make_uint4(0,0,0,0);
      if (!oob){
        f32x16 acc;
        #pragma unroll
        for (int r = 0; r < 16; ++r) acc[r] = 0.f;
        #pragma unroll
        for (int dy = 0; dy < 5; ++dy){
          const u32* rp = &ilds[(idx + dy)*C1_ROWW + px + hi*4];
          union { u32 uw[4]; bf16x8 v; } ub;
          ub.uw[0] = rp[0]; ub.uw[1] = rp[1]; ub.uw[2] = rp[2]; ub.uw[3] = rp[3];
          acc = __builtin_amdgcn_mfma_f32_32x32x16_bf16(afr[dy], ub.v, acc, 0, 0, 0);
        }
        u32 wd[4];
        #pragma unroll
        for (int qd = 0; qd < 4; ++qd){
          u32 word = pk_fp8<false>(fmaxf(acc[4*qd+0]+b1v[4*qd+0], 0.f),
                                   fmaxf(acc[4*qd+1]+b1v[4*qd+1], 0.f), 0u);
          word = pk_fp8<true>(fmaxf(acc[4*qd+2]+b1v[4*qd+2], 0.f),
                              fmaxf(acc[4*qd+3]+b1v[4*qd+3], 0.f), word);
          wd[qd] = word;
        }
        st.x = wd[0]; st.y = wd[1]; st.z = wd[2]; st.w = wd[3];
      }
      int lx = px + 2;
      int addr = idx*C2_IN_ROWB + (((lx << 5) + (hi << 4)) ^ ((lx & 7) << 4));
      *(uint4*)(c2in + addr) = st;
    }
  }
  __syncthreads();
  // ---- conv2 phase (MX-scaled fp8, K=64, unit scales), A-frags from global
  f32x16 acc[4];
  #pragma unroll
  for (int t = 0; t < 4; ++t)
    #pragma unroll
    for (int r = 0; r < 16; ++r) acc[t][r] = 0.f;
  #pragma unroll
  for (int dy = 0; dy < 5; ++dy){
    const char* rowp = c2in + (w + dy)*C2_IN_ROWB;
    ll2 aw[5];
    #pragma unroll
    for (int dx = 0; dx < 5; ++dx)
      aw[dx] = *(const ll2*)(w2p + (dy*5 + dx)*1024 + aSwz);
#ifdef HAVE_MXFP8
    union U8x { struct { ll2 lo, hi; } p; i32x8 v; };
    U8x a01, a23, a4z;
    ll2 zz; zz.x = 0; zz.y = 0;
    a01.p.lo = aw[0]; a01.p.hi = aw[1];
    a23.p.lo = aw[2]; a23.p.hi = aw[3];
    a4z.p.lo = aw[4]; a4z.p.hi = zz;
    #pragma unroll
    for (int t = 0; t < 4; ++t){
      int pxb = t*32 + l31;
      ll2 bl[5];
      #pragma unroll
      for (int dx = 0; dx < 5; ++dx){
        int px2 = pxb + dx;
        int boff = ((px2 << 5) + (hi << 4)) ^ ((px2 & 7) << 4);
        bl[dx] = *(const ll2*)(rowp + boff);
      }
      U8x b01, b23, b4d;
      b01.p.lo = bl[0]; b01.p.hi = bl[1];
      b23.p.lo = bl[2]; b23.p.hi = bl[3];
      b4d.p.lo = bl[4]; b4d.p.hi = bl[4];
      __builtin_amdgcn_s_setprio(1);
      acc[t] = __builtin_amdgcn_mfma_scale_f32_32x32x64_f8f6f4(
                 a01.v, b01.v, acc[t], 0, 0, 0, 0x7F7F7F7F, 0, 0x7F7F7F7F);
      acc[t] = __builtin_amdgcn_mfma_scale_f32_32x32x64_f8f6f4(
                 a23.v, b23.v, acc[t], 0, 0, 0, 0x7F7F7F7F, 0, 0x7F7F7F7F);
      acc[t] = __builtin_amdgcn_mfma_scale_f32_32x32x64_f8f6f4(
                 a4z.v, b4d.v, acc[t], 0, 0, 0, 0x7F7F7F7F, 0, 0x7F7F7F7F);
      __builtin_amdgcn_s_setprio(0);
    }
#else
    #pragma unroll
    for (int dx = 0; dx < 5; ++dx){
      ll2 a = aw[dx];
      #pragma unroll
      for (int t = 0; t < 4; ++t){
        int px2 = t*32 + l31 + dx;
        int boff = ((px2 << 5) + (hi << 4)) ^ ((px2 & 7) << 4);
        ll2 b = *(const ll2*)(rowp + boff);
        acc[t] = __builtin_amdgcn_mfma_f32_32x32x16_fp8_fp8(a.x, b.x, acc[t], 0, 0, 0);
        acc[t] = __builtin_amdgcn_mfma_f32_32x32x16_fp8_fp8(a.y, b.y, acc[t], 0, 0, 0);
      }
    }
#endif
  }
  float b2v[16];
  #pragma unroll
  for (int r = 0; r < 16; ++r){
    int oc = (r & 3) + 8*(r >> 2) + 4*hi;
    b2v[r] = (oc < MC) ? b2[oc] : 0.f;
  }
  __syncthreads();
  int wbase = w * 4096;
  #pragma unroll
  for (int t = 0; t < 4; ++t){
    int px = t*32 + l31;
    u32 wd[4];
    #pragma unroll
    for (int qd = 0; qd < 4; ++qd){
      float v0 = fmaxf(acc[t][4*qd+0] + b2v[4*qd+0], 0.f);
      float v1 = fmaxf(acc[t][4*qd+1] + b2v[4*qd+1], 0.f);
      float v2 = fmaxf(acc[t][4*qd+2] + b2v[4*qd+2], 0.f);
      float v3 = fmaxf(acc[t][4*qd+3] + b2v[4*qd+3], 0.f);
      u32 word = pk_fp8<false>(v0, v1, 0u);
      word = pk_fp8<true>(v2, v3, word);
      wd[qd] = word;
    }
    uint4 st; st.x = wd[0]; st.y = wd[1]; st.z = wd[2]; st.w = wd[3];
    int addr = wbase + (((px << 5) + (hi << 4)) ^ ((px & 7) << 4));
    *(uint4*)(c2in + addr) = st;
  }
  int y = y0 + w;
  #pragma unroll
  for (int p = 0; p < 8; ++p){
    int x = p*16 + (lane >> 2), cg = lane & 3;
    int addr = wbase + (((x << 5) + (cg << 3)) ^ ((x & 7) << 4));
    uint2 v = *(const uint2*)(c2in + addr);
    *(uint2*)(act2 + ((((size_t)bb*128 + y)*128 + x) << 5) + cg*8) = v;
  }
}

// ---------------- conv3 + mask + row softmax + A write + fused dis atomics ----------------
__global__ __launch_bounds__(512) void conv3sm_k(const u8* __restrict__ act2,
    const float* __restrict__ w3, const float* __restrict__ b3, const float* __restrict__ Dbuf,
    const int* __restrict__ qlen, const int* __restrict__ klen,
    float* __restrict__ Aout, float* __restrict__ out_dis, int b0){
  __shared__ float wlds[9][32];
  __shared__ float ex0[512], ex2[512];
  __shared__ float redm[8], reds[8], redd[8];
  int o  = blockIdx.x;                    // 0..63
  int ip = ((o & 7) << 3) + (o >> 3);     // XCD-chunked row-pair index
  int bb = blockIdx.y;
  int b  = b0 + bb;
  int tid = threadIdx.x;
  for (int idx = tid; idx < 288; idx += 512){
    int tap = idx >> 5, p = idx & 31;
    int cp = 8*((p >> 2) & 3) + 4*(p >> 4) + (p & 3);   // channel stored at byte p
    wlds[tap][p] = (cp < MC) ? w3[cp * 9 + tap] : 0.f;
  }
  __syncthreads();
  int r  = tid >> 8;
  int t  = tid & 255;
  int px = t >> 1, half = t & 1;
  int i  = ip * 2 + r;
  int wv = tid >> 6;
  float T0 = 0.f, T1 = 0.f, T2 = 0.f;
  #pragma unroll
  for (int dy = 0; dy < 3; ++dy){
    int gy = i - 1 + dy;
    uint4 v = make_uint4(0, 0, 0, 0);
    if ((unsigned)gy < 128u)
      v = *(const uint4*)(act2 + ((((size_t)bb*128 + gy)*128 + px) << 5) + half*16);
    float x[16];
    upk_fp8x4(v.x, x); upk_fp8x4(v.y, x + 4);
    upk_fp8x4(v.z, x + 8); upk_fp8x4(v.w, x + 12);
    const float* w0p = &wlds[dy*3 + 0][half*16];
    const float* w1p = &wlds[dy*3 + 1][half*16];
    const float* w2q = &wlds[dy*3 + 2][half*16];
    #pragma unroll
    for (int c = 0; c < 16; ++c){
      T0 = fmaf(x[c], w0p[c], T0);
      T1 = fmaf(x[c], w1p[c], T1);
      T2 = fmaf(x[c], w2q[c], T2);
    }
  }
  ex0[tid] = T0; ex2[tid] = T2;
  __syncthreads();
  float acc = T1;
  if (px > 0)   acc += ex0[tid - 2];
  if (px < 127) acc += ex2[tid + 2];
  acc += __shfl_xor(acc, 1);
  acc += b3[0];
  float Dv = Dbuf[(((size_t)b * 128 + i) << 7) + px];
  bool m = (i < qlen[b]) && (px < klen[b]);
  float xv = m ? -(acc + Dv) : -100.f;
  float mx = xv;
  #pragma unroll
  for (int o2 = 32; o2; o2 >>= 1) mx = fmaxf(mx, __shfl_xor(mx, o2));
  if ((tid & 63) == 0) redm[wv] = mx;
  __syncthreads();
  int rb4 = r << 2;
  mx = fmaxf(fmaxf(redm[rb4], redm[rb4+1]), fmaxf(redm[rb4+2], redm[rb4+3]));
  float e = __expf(xv - mx);
  float s  = e;
  float de = Dv * e;
  #pragma unroll
  for (int o2 = 32; o2; o2 >>= 1){ s += __shfl_xor(s, o2); de += __shfl_xor(de, o2); }
  if ((tid & 63) == 0){ reds[wv] = s; redd[wv] = de; }
  __syncthreads();
  float s4 = (reds[rb4] + reds[rb4+1]) + (reds[rb4+2] + reds[rb4+3]);
  float a = e * 2.0f / s4;
  if (half == 0) Aout[(((size_t)b * 128 + i) << 7) + px] = a;
  if (t == 0){
    float d4 = (redd[rb4] + redd[rb4+1]) + (redd[rb4+2] + redd[rb4+3]);
    atomicAdd(&out_dis[b], (d4 / s4) * (1.0f / 128.0f));
  }
}

extern "C" void kernel_launch(void* const* d_in, const int* in_sizes, int n_in,
                              void* d_out, int out_size, void* d_ws, size_t ws_size,
                              hipStream_t stream){
  const float* q_seq = (const float*)d_in[0];
  const int*   q_len = (const int*)d_in[1];
  const float* q_R   = (const float*)d_in[2];
  const float* k_seq = (const float*)d_in[3];
  const int*   k_len = (const int*)d_in[4];
  const float* k_R   = (const float*)d_in[5];
  const float* c1w   = (const float*)d_in[6];
  const float* c1b   = (const float*)d_in[7];
  const float* c2w   = (const float*)d_in[8];
  const float* c2b   = (const float*)d_in[9];
  const float* c3w   = (const float*)d_in[10];
  const float* c3b   = (const float*)d_in[11];
  float* out = (float*)d_out;
  float* out_dis = out + (size_t)NB * TT * TT;

  char* base = (char*)d_ws;
  size_t off = 0;
  auto take = [&](size_t bytes)->char*{
    char* p = base + off;
    off = (off + bytes + 255) & ~(size_t)255;
    return p;
  };
  float* Dbuf   = (float*)take((size_t)NB * TT * TT * 4);
  float* qq     = (float*)take((size_t)NB * TT * 4);
  float* kkn    = (float*)take((size_t)NB * TT * 4);
  u32*   inb    = (u32*)  take((size_t)NB * TT * TT * 4);
  u8*    w2p    = (u8*)   take(25 * 1024);
  u16*   w1c    = (u16*)  take(5 * 1024);
  u16*   qb16   = (u16*)  take((size_t)NB * TT * DK * 2);
  u16*   kb16   = (u16*)  take((size_t)NB * TT * DK * 2);
  size_t fixed = off;
  int BCH = 64;
  while (BCH > 1 && fixed + (size_t)BCH * TT * TT * 32 + 1024 > ws_size) BCH >>= 1;
  u8* act2 = (u8*)take((size_t)BCH * TT * TT * 32);

  row_norms_k<<<4123, 256, 0, stream>>>(q_seq, k_seq, qq, kkn, qb16, kb16, c2w, c1w, w2p, w1c, out_dis);
  cdist_mfma_k<<<256, 256, 0, stream>>>(qb16, kb16, qq, kkn, q_len, k_len, q_R, k_R, Dbuf, inb);
  for (int b0 = 0; b0 < NB; b0 += BCH){
    int nb = BCH;
    conv12_mfma_k<<<dim3(16, nb), 512, 0, stream>>>(inb + (size_t)b0 * TT * TT, w2p, w1c, c1b, c2b, act2);
    conv3sm_k<<<dim3(64, nb), 512, 0, stream>>>(act2, c3w, c3b, Dbuf, q_len, k_len, out, out_dis, b0);
  }
}

// Round 24
// 136.376 us; speedup vs baseline: 1.4394x; 1.4394x over previous
//
#include <hip/hip_runtime.h>
#include <hip/hip_bf16.h>
#include <stdint.h>

using u16 = unsigned short;
using u32 = unsigned int;
using u8  = unsigned char;

#define NB 64
#define TT 128
#define DK 768
#define MC 30

typedef float f32x16 __attribute__((ext_vector_type(16)));
typedef __bf16 bf16x8 __attribute__((ext_vector_type(8)));
typedef long long ll;
typedef __attribute__((ext_vector_type(2))) ll ll2;
#if __has_builtin(__builtin_amdgcn_mfma_scale_f32_32x32x64_f8f6f4)
#define HAVE_MXFP8 1
typedef int i32x8 __attribute__((ext_vector_type(8)));
#endif
#if __has_builtin(__builtin_amdgcn_global_load_lds)
#define HAVE_GLDS 1
#endif

__device__ inline void unpack2(u32 u, float& lo, float& hi){
  union{u32 i; float f;} a, b; a.i = u << 16; b.i = u & 0xFFFF0000u; lo = a.f; hi = b.f;
}
__device__ inline u16 f2bf(float f){
  union{u32 i; float f;} v; v.f = f;
  u32 r = v.i + 0x7FFFu + ((v.i >> 16) & 1u);
  return (u16)(r >> 16);
}
__device__ inline u32 pack2bf(float a, float b){ return (u32)f2bf(a) | ((u32)f2bf(b) << 16); }

// ---------------- fp8 e4m3fn pack/unpack helpers ----------------
#if __has_builtin(__builtin_amdgcn_cvt_pk_fp8_f32)
template<bool HIW>
__device__ inline u32 pk_fp8(float a, float b, u32 old){
  return (u32)__builtin_amdgcn_cvt_pk_fp8_f32(a, b, (int)old, HIW);
}
#else
__device__ inline u8 f2fp8_1(float f){
  union{float f; u32 u;} v; v.f = f;
  u32 s = (v.u >> 24) & 0x80u;
  u32 abs = v.u & 0x7fffffffu;
  if (abs < 0x3c800000u){
    float sc = fabsf(f) * 512.0f;
    int m = (int)rintf(sc);
    return (u8)(s | (u32)m);
  }
  u32 e8 = abs >> 23; u32 mant = abs & 0x7fffffu;
  u32 m3 = mant >> 20; u32 rest = mant & 0xfffffu;
  u32 rb = (rest > 0x80000u) || (rest == 0x80000u && (m3 & 1u));
  m3 += rb;
  u32 E = e8 - 120u;
  if (m3 == 8u){ m3 = 0u; E += 1u; }
  if (E >= 16u || (E == 15u && m3 == 7u)) return (u8)(s | 0x7Eu);
  return (u8)(s | (E << 3) | m3);
}
template<bool HIW>
__device__ inline u32 pk_fp8(float a, float b, u32 old){
  u32 w = (u32)f2fp8_1(a) | ((u32)f2fp8_1(b) << 8);
  return HIW ? ((old & 0x0000FFFFu) | (w << 16)) : ((old & 0xFFFF0000u) | w);
}
#endif

#if __has_builtin(__builtin_amdgcn_cvt_pk_f32_fp8)
__device__ inline void upk_fp8x4(u32 w, float* x){
  auto a0 = __builtin_amdgcn_cvt_pk_f32_fp8((int)w, false);
  auto a1 = __builtin_amdgcn_cvt_pk_f32_fp8((int)w, true);
  x[0] = a0[0]; x[1] = a0[1]; x[2] = a1[0]; x[3] = a1[1];
}
#else
__device__ inline float fp8_1(u32 byte){
  u32 s = (byte & 0x80u) << 24;
  u32 E = (byte >> 3) & 15u, M = byte & 7u;
  union{u32 u; float f;} v;
  if (E == 0){ v.f = (float)M * (1.0f/512.0f); v.u |= s; }
  else v.u = s | ((E + 120u) << 23) | (M << 20);
  return v.f;
}
__device__ inline void upk_fp8x4(u32 w, float* x){
  x[0] = fp8_1(w & 255u); x[1] = fp8_1((w >> 8) & 255u);
  x[2] = fp8_1((w >> 16) & 255u); x[3] = fp8_1(w >> 24);
}
#endif

// ic PERMUTATION (applied identically to w2p, c2in, act2, conv3 weights):
// channel c = 8q + 4h + j  lives at byte p = h*16 + q*4 + j   (q,j in 0..3, h in 0..1)

// ---------------- kernel 1: row norms + bf16 conversion (PRE-SWIZZLED output)
//                  + fused weight prep (blocks >= 4096) + dis zero-init ----------------
__global__ __launch_bounds__(256) void row_norms_k(const float* __restrict__ q, const float* __restrict__ k,
    float* __restrict__ qq, float* __restrict__ kk,
    u16* __restrict__ qb16, u16* __restrict__ kb16,
    const float* __restrict__ w2, const float* __restrict__ w1,
    u8* __restrict__ w2p, u16* __restrict__ w1c, float* __restrict__ out_dis){
  if (blockIdx.x >= 4096){
    int bidx = blockIdx.x - 4096;
    if (bidx < 25){
      int tap = bidx;
      int i = threadIdx.x;
      int oc = i >> 3, qd = i & 7;
      int ic0 = 8*(qd & 3) + 4*(qd >> 2);   // permuted: byte qd*4 holds channels ic0..ic0+3
      float v[4];
      #pragma unroll
      for (int j = 0; j < 4; ++j)
        v[j] = (oc < MC && ic0 + j < MC) ? w2[(oc*MC + ic0 + j)*25 + tap] : 0.f;
      u32 w = pk_fp8<false>(v[0], v[1], 0u);
      w = pk_fp8<true>(v[2], v[3], w);
      int lo = ((oc << 5) + (qd << 2)) ^ ((oc & 7) << 4);
      *(u32*)(w2p + tap*1024 + lo) = w;
    } else if (bidx == 25){
      for (int i = threadIdx.x; i < 2560; i += 256){
        int dy = i >> 9; int rem = i & 511; int oc = rem >> 4; int kx = rem & 15;
        int dx = kx >> 1, c = kx & 1;
        float v = (oc < MC && dx < 5) ? w1[(oc*2 + c)*25 + dy*5 + dx] : 0.f;
        int byteoff = dy*1024 + (((oc<<5) + (kx<<1)) ^ ((oc&7)<<4));
        *(u16*)((char*)w1c + byteoff) = f2bf(v);
      }
    } else {
      if (threadIdx.x < NB) out_dis[threadIdx.x] = 0.f;
    }
    return;
  }
  int wave = blockIdx.x * 4 + (threadIdx.x >> 6);
  int lane = threadIdx.x & 63;
  const float* src; float* dst; u16* bdst; int row;
  if (wave < NB * TT) { src = q; dst = qq; bdst = qb16; row = wave; }
  else                { src = k; dst = kk; bdst = kb16; row = wave - NB * TT; }
  const float4* p = (const float4*)(src + (size_t)row * DK);
  char* ob = (char*)(bdst + (size_t)row * DK);
  int key = (row & 7) << 4;
  float s = 0.f;
  {
    float4 a = p[2*lane], b2 = p[2*lane + 1];
    s += a.x*a.x + a.y*a.y + a.z*a.z + a.w*a.w;
    s += b2.x*b2.x + b2.y*b2.y + b2.z*b2.z + b2.w*b2.w;
    uint4 st;
    st.x = pack2bf(a.x, a.y);  st.y = pack2bf(a.z, a.w);
    st.z = pack2bf(b2.x, b2.y); st.w = pack2bf(b2.z, b2.w);
    *(uint4*)(ob + ((lane << 4) ^ key)) = st;
  }
  if (lane < 32){
    int g = 64 + lane;
    float4 a = p[2*g], b2 = p[2*g + 1];
    s += a.x*a.x + a.y*a.y + a.z*a.z + a.w*a.w;
    s += b2.x*b2.x + b2.y*b2.y + b2.z*b2.z + b2.w*b2.w;
    uint4 st;
    st.x = pack2bf(a.x, a.y);  st.y = pack2bf(a.z, a.w);
    st.z = pack2bf(b2.x, b2.y); st.w = pack2bf(b2.z, b2.w);
    *(uint4*)(ob + ((g << 4) ^ key)) = st;
  }
  #pragma unroll
  for (int o = 32; o; o >>= 1) s += __shfl_xor(s, o);
  if (lane == 0) dst[row] = s;
}

// ---------------- kernel 2: cdist via bf16 MFMA, async linear staging, XCD-grouped grid ----------------
__global__ __launch_bounds__(256) void cdist_mfma_k(
    const u16* __restrict__ Qb16, const u16* __restrict__ Kb16,
    const float* __restrict__ qq, const float* __restrict__ kk,
    const int* __restrict__ qlen, const int* __restrict__ klen,
    const float* __restrict__ qR, const float* __restrict__ kR,
    float* __restrict__ Dout, u32* __restrict__ inb){
  __shared__ __align__(16) char qs[32 * 1536];
  __shared__ __align__(16) char ksm[128 * 256];
  int bid = blockIdx.x;
  int b  = ((bid & 7) << 3) + (bid >> 5);
  int rt = (bid >> 3) & 3;
  int r0 = rt * 32;
  int tid = threadIdx.x;
  int lane = tid & 63, w = tid >> 6;
  int hi = lane >> 5, l31 = lane & 31;
  const char* Qg = (const char*)(Qb16 + ((size_t)b * TT + r0) * DK);
  const char* Kg = (const char*)(Kb16 + (size_t)b * TT * DK);
#ifdef HAVE_GLDS
  #pragma unroll
  for (int i = 0; i < 12; ++i){
    int gb = (i*4 + w) << 6;
    __builtin_amdgcn_global_load_lds((const u32*)(Qg + ((gb + lane) << 4)),
                                     (u32*)(qs + (gb << 4)), 16, 0, 0);
  }
#else
  for (int idx = tid; idx < 3072; idx += 256)
    *(uint4*)(qs + idx*16) = *(const uint4*)(Qg + idx*16);
#endif
  int col = w * 32 + l31;
  f32x16 acc;
  #pragma unroll
  for (int r = 0; r < 16; ++r) acc[r] = 0.f;
  for (int kc = 0; kc < DK; kc += 128){
    __syncthreads();
#ifdef HAVE_GLDS
    const char* Ks = Kg + kc*2;
    #pragma unroll
    for (int i = 0; i < 8; ++i){
      int gb = (i*4 + w) << 6;
      int g = gb + lane;
      __builtin_amdgcn_global_load_lds((const u32*)(Ks + (g >> 4)*1536 + ((g & 15) << 4)),
                                       (u32*)(ksm + (gb << 4)), 16, 0, 0);
    }
#else
    for (int idx = tid; idx < 2048; idx += 256){
      int c = idx >> 4, j = idx & 15;
      *(uint4*)(ksm + idx*16) = *(const uint4*)(Kg + c*1536 + kc*2 + j*16);
    }
#endif
    __syncthreads();
    #pragma unroll
    for (int k8 = 0; k8 < 8; ++k8){
      bf16x8 a  = *(const bf16x8*)(qs  + l31 * 1536 + (((kc + k8*16 + hi*8) * 2) ^ ((l31 & 7) << 4)));
      bf16x8 bv = *(const bf16x8*)(ksm + col * 256  + (((k8*16 + hi*8) * 2) ^ ((col & 7) << 4)));
      acc = __builtin_amdgcn_mfma_f32_32x32x16_bf16(a, bv, acc, 0, 0, 0);
    }
  }
  int ql = qlen[b], kl = klen[b];
  float kkv = kk[b * TT + col];
  float krv = kR[b * TT + col];
  bool cm = col < kl;
  #pragma unroll
  for (int r = 0; r < 16; ++r){
    int row = r0 + (r & 3) + 8 * (r >> 2) + 4 * hi;
    float qqv = qq[b * TT + row];
    float sq = qqv + kkv - 2.f * acc[r];
    float d = sqrtf(fmaxf(sq, 1e-12f));
    bool m = (row < ql) && cm;
    float dm = m ? d : 0.f;
    float pm = m ? fabsf(qR[b * TT + row] - krv) : 0.f;
    Dout[(((size_t)b * TT + row) << 7) + col] = dm;
    inb[(((size_t)b * TT + row) << 7) + col] = pack2bf(dm, pm);
  }
}

// ---------------- fused conv1+conv2 (permuted-ic contiguous stores, NO setprio) ----------------
#define C1_ROWW 136
#define C2_IN_ROWB 4224                 // 132 px * 32 B
#define F_INB_BYTES (16*C1_ROWW*4)      // 8704
#define F_C2_OFF F_INB_BYTES
#define F_SMEM (F_INB_BYTES + 12*C2_IN_ROWB)   // 59392

__global__ __launch_bounds__(512, 4) void conv12_mfma_k(
    const u32* __restrict__ inb, const u8* __restrict__ w2p, const u16* __restrict__ w1c,
    const float* __restrict__ b1, const float* __restrict__ b2, u8* __restrict__ act2){
  __shared__ __align__(16) char smem[F_SMEM];
  u32* ilds = (u32*)smem;
  char* c2in = smem + F_C2_OFF;
  int o  = blockIdx.x;
  int yg = ((o & 7) << 1) + (o >> 3);
  int bb = blockIdx.y;
  int y0 = yg * 8;
  int tid = threadIdx.x;
  for (int i = tid; i < 16*C1_ROWW; i += 512){
    int r = i / C1_ROWW, xi = i - r * C1_ROWW;
    int gy = y0 - 4 + r, gx = xi - 2;
    u32 v = 0;
    if ((unsigned)gy < 128u && (unsigned)gx < 128u)
      v = inb[(((size_t)bb * 128 + gy) << 7) + gx];
    ilds[r * C1_ROWW + xi] = v;
  }
  for (int i = tid; i < 96; i += 512){
    int r = i >> 3; int rem = i & 7; int ci = rem >> 1; int h = rem & 1;
    int lx = (ci < 2) ? ci : (128 + ci);
    int addr = r*C2_IN_ROWB + (((lx << 5) + (h << 4)) ^ ((lx & 7) << 4));
    *(uint4*)(c2in + addr) = make_uint4(0,0,0,0);
  }
  int lane = tid & 63, w = tid >> 6;
  int hi = lane >> 5, l31 = lane & 31;
  int aSwz = ((l31 << 5) + (hi << 4)) ^ ((l31 & 7) << 4);
  bf16x8 afr[5];
  #pragma unroll
  for (int dy = 0; dy < 5; ++dy)
    afr[dy] = *(const bf16x8*)((const char*)w1c + dy*1024 + aSwz);
  float b1v[16];
  #pragma unroll
  for (int r = 0; r < 16; ++r){
    int oc = (r & 3) + 8*(r >> 2) + 4*hi;
    b1v[r] = (oc < MC) ? b1[oc] : 0.f;
  }
  __syncthreads();
  // ---- conv1 phase: 1 contiguous uint4 store per (lane, tile)
  for (int rep = 0; rep < 2; ++rep){
    if (rep == 1 && w >= 4) break;
    int idx = (rep == 0) ? w : (8 + w);
    int gy = y0 - 2 + idx;
    bool oob = (unsigned)gy >= 128u;
    #pragma unroll
    for (int t = 0; t < 4; ++t){
      int px = t*32 + l31;
      uint4 st = make_uint4(0,0,0,0);
      if (!oob){
        f32x16 acc;
        #pragma unroll
        for (int r = 0; r < 16; ++r) acc[r] = 0.f;
        #pragma unroll
        for (int dy = 0; dy < 5; ++dy){
          const u32* rp = &ilds[(idx + dy)*C1_ROWW + px + hi*4];
          union { u32 uw[4]; bf16x8 v; } ub;
          ub.uw[0] = rp[0]; ub.uw[1] = rp[1]; ub.uw[2] = rp[2]; ub.uw[3] = rp[3];
          acc = __builtin_amdgcn_mfma_f32_32x32x16_bf16(afr[dy], ub.v, acc, 0, 0, 0);
        }
        u32 wd[4];
        #pragma unroll
        for (int qd = 0; qd < 4; ++qd){
          u32 word = pk_fp8<false>(fmaxf(acc[4*qd+0]+b1v[4*qd+0], 0.f),
                                   fmaxf(acc[4*qd+1]+b1v[4*qd+1], 0.f), 0u);
          word = pk_fp8<true>(fmaxf(acc[4*qd+2]+b1v[4*qd+2], 0.f),
                              fmaxf(acc[4*qd+3]+b1v[4*qd+3], 0.f), word);
          wd[qd] = word;
        }
        st.x = wd[0]; st.y = wd[1]; st.z = wd[2]; st.w = wd[3];
      }
      int lx = px + 2;
      int addr = idx*C2_IN_ROWB + (((lx << 5) + (hi << 4)) ^ ((lx & 7) << 4));
      *(uint4*)(c2in + addr) = st;
    }
  }
  __syncthreads();
  // ---- conv2 phase (MX-scaled fp8, K=64, unit scales), A-frags from global
  f32x16 acc[4];
  #pragma unroll
  for (int t = 0; t < 4; ++t)
    #pragma unroll
    for (int r = 0; r < 16; ++r) acc[t][r] = 0.f;
  #pragma unroll
  for (int dy = 0; dy < 5; ++dy){
    const char* rowp = c2in + (w + dy)*C2_IN_ROWB;
    ll2 aw[5];
    #pragma unroll
    for (int dx = 0; dx < 5; ++dx)
      aw[dx] = *(const ll2*)(w2p + (dy*5 + dx)*1024 + aSwz);
#ifdef HAVE_MXFP8
    union U8x { struct { ll2 lo, hi; } p; i32x8 v; };
    U8x a01, a23, a4z;
    ll2 zz; zz.x = 0; zz.y = 0;
    a01.p.lo = aw[0]; a01.p.hi = aw[1];
    a23.p.lo = aw[2]; a23.p.hi = aw[3];
    a4z.p.lo = aw[4]; a4z.p.hi = zz;
    #pragma unroll
    for (int t = 0; t < 4; ++t){
      int pxb = t*32 + l31;
      ll2 bl[5];
      #pragma unroll
      for (int dx = 0; dx < 5; ++dx){
        int px2 = pxb + dx;
        int boff = ((px2 << 5) + (hi << 4)) ^ ((px2 & 7) << 4);
        bl[dx] = *(const ll2*)(rowp + boff);
      }
      U8x b01, b23, b4d;
      b01.p.lo = bl[0]; b01.p.hi = bl[1];
      b23.p.lo = bl[2]; b23.p.hi = bl[3];
      b4d.p.lo = bl[4]; b4d.p.hi = bl[4];
      acc[t] = __builtin_amdgcn_mfma_scale_f32_32x32x64_f8f6f4(
                 a01.v, b01.v, acc[t], 0, 0, 0, 0x7F7F7F7F, 0, 0x7F7F7F7F);
      acc[t] = __builtin_amdgcn_mfma_scale_f32_32x32x64_f8f6f4(
                 a23.v, b23.v, acc[t], 0, 0, 0, 0x7F7F7F7F, 0, 0x7F7F7F7F);
      acc[t] = __builtin_amdgcn_mfma_scale_f32_32x32x64_f8f6f4(
                 a4z.v, b4d.v, acc[t], 0, 0, 0, 0x7F7F7F7F, 0, 0x7F7F7F7F);
    }
#else
    #pragma unroll
    for (int dx = 0; dx < 5; ++dx){
      ll2 a = aw[dx];
      #pragma unroll
      for (int t = 0; t < 4; ++t){
        int px2 = t*32 + l31 + dx;
        int boff = ((px2 << 5) + (hi << 4)) ^ ((px2 & 7) << 4);
        ll2 b = *(const ll2*)(rowp + boff);
        acc[t] = __builtin_amdgcn_mfma_f32_32x32x16_fp8_fp8(a.x, b.x, acc[t], 0, 0, 0);
        acc[t] = __builtin_amdgcn_mfma_f32_32x32x16_fp8_fp8(a.y, b.y, acc[t], 0, 0, 0);
      }
    }
#endif
  }
  float b2v[16];
  #pragma unroll
  for (int r = 0; r < 16; ++r){
    int oc = (r & 3) + 8*(r >> 2) + 4*hi;
    b2v[r] = (oc < MC) ? b2[oc] : 0.f;
  }
  __syncthreads();
  int wbase = w * 4096;
  #pragma unroll
  for (int t = 0; t < 4; ++t){
    int px = t*32 + l31;
    u32 wd[4];
    #pragma unroll
    for (int qd = 0; qd < 4; ++qd){
      float v0 = fmaxf(acc[t][4*qd+0] + b2v[4*qd+0], 0.f);
      float v1 = fmaxf(acc[t][4*qd+1] + b2v[4*qd+1], 0.f);
      float v2 = fmaxf(acc[t][4*qd+2] + b2v[4*qd+2], 0.f);
      float v3 = fmaxf(acc[t][4*qd+3] + b2v[4*qd+3], 0.f);
      u32 word = pk_fp8<false>(v0, v1, 0u);
      word = pk_fp8<true>(v2, v3, word);
      wd[qd] = word;
    }
    uint4 st; st.x = wd[0]; st.y = wd[1]; st.z = wd[2]; st.w = wd[3];
    int addr = wbase + (((px << 5) + (hi << 4)) ^ ((px & 7) << 4));
    *(uint4*)(c2in + addr) = st;
  }
  int y = y0 + w;
  #pragma unroll
  for (int p = 0; p < 8; ++p){
    int x = p*16 + (lane >> 2), cg = lane & 3;
    int addr = wbase + (((x << 5) + (cg << 3)) ^ ((x & 7) << 4));
    uint2 v = *(const uint2*)(c2in + addr);
    *(uint2*)(act2 + ((((size_t)bb*128 + y)*128 + x) << 5) + cg*8) = v;
  }
}

// ---------------- conv3 + mask + row softmax + A write + fused dis atomics ----------------
__global__ __launch_bounds__(512) void conv3sm_k(const u8* __restrict__ act2,
    const float* __restrict__ w3, const float* __restrict__ b3, const float* __restrict__ Dbuf,
    const int* __restrict__ qlen, const int* __restrict__ klen,
    float* __restrict__ Aout, float* __restrict__ out_dis, int b0){
  __shared__ float wlds[9][32];
  __shared__ float ex0[512], ex2[512];
  __shared__ float redm[8], reds[8], redd[8];
  int o  = blockIdx.x;                    // 0..63
  int ip = ((o & 7) << 3) + (o >> 3);     // XCD-chunked row-pair index
  int bb = blockIdx.y;
  int b  = b0 + bb;
  int tid = threadIdx.x;
  for (int idx = tid; idx < 288; idx += 512){
    int tap = idx >> 5, p = idx & 31;
    int cp = 8*((p >> 2) & 3) + 4*(p >> 4) + (p & 3);   // channel stored at byte p
    wlds[tap][p] = (cp < MC) ? w3[cp * 9 + tap] : 0.f;
  }
  __syncthreads();
  int r  = tid >> 8;
  int t  = tid & 255;
  int px = t >> 1, half = t & 1;
  int i  = ip * 2 + r;
  int wv = tid >> 6;
  float T0 = 0.f, T1 = 0.f, T2 = 0.f;
  #pragma unroll
  for (int dy = 0; dy < 3; ++dy){
    int gy = i - 1 + dy;
    uint4 v = make_uint4(0, 0, 0, 0);
    if ((unsigned)gy < 128u)
      v = *(const uint4*)(act2 + ((((size_t)bb*128 + gy)*128 + px) << 5) + half*16);
    float x[16];
    upk_fp8x4(v.x, x); upk_fp8x4(v.y, x + 4);
    upk_fp8x4(v.z, x + 8); upk_fp8x4(v.w, x + 12);
    const float* w0p = &wlds[dy*3 + 0][half*16];
    const float* w1p = &wlds[dy*3 + 1][half*16];
    const float* w2q = &wlds[dy*3 + 2][half*16];
    #pragma unroll
    for (int c = 0; c < 16; ++c){
      T0 = fmaf(x[c], w0p[c], T0);
      T1 = fmaf(x[c], w1p[c], T1);
      T2 = fmaf(x[c], w2q[c], T2);
    }
  }
  ex0[tid] = T0; ex2[tid] = T2;
  __syncthreads();
  float acc = T1;
  if (px > 0)   acc += ex0[tid - 2];
  if (px < 127) acc += ex2[tid + 2];
  acc += __shfl_xor(acc, 1);
  acc += b3[0];
  float Dv = Dbuf[(((size_t)b * 128 + i) << 7) + px];
  bool m = (i < qlen[b]) && (px < klen[b]);
  float xv = m ? -(acc + Dv) : -100.f;
  float mx = xv;
  #pragma unroll
  for (int o2 = 32; o2; o2 >>= 1) mx = fmaxf(mx, __shfl_xor(mx, o2));
  if ((tid & 63) == 0) redm[wv] = mx;
  __syncthreads();
  int rb4 = r << 2;
  mx = fmaxf(fmaxf(redm[rb4], redm[rb4+1]), fmaxf(redm[rb4+2], redm[rb4+3]));
  float e = __expf(xv - mx);
  float s  = e;
  float de = Dv * e;
  #pragma unroll
  for (int o2 = 32; o2; o2 >>= 1){ s += __shfl_xor(s, o2); de += __shfl_xor(de, o2); }
  if ((tid & 63) == 0){ reds[wv] = s; redd[wv] = de; }
  __syncthreads();
  float s4 = (reds[rb4] + reds[rb4+1]) + (reds[rb4+2] + reds[rb4+3]);
  float a = e * 2.0f / s4;
  if (half == 0) Aout[(((size_t)b * 128 + i) << 7) + px] = a;
  if (t == 0){
    float d4 = (redd[rb4] + redd[rb4+1]) + (redd[rb4+2] + redd[rb4+3]);
    atomicAdd(&out_dis[b], (d4 / s4) * (1.0f / 128.0f));
  }
}

extern "C" void kernel_launch(void* const* d_in, const int* in_sizes, int n_in,
                              void* d_out, int out_size, void* d_ws, size_t ws_size,
                              hipStream_t stream){
  const float* q_seq = (const float*)d_in[0];
  const int*   q_len = (const int*)d_in[1];
  const float* q_R   = (const float*)d_in[2];
  const float* k_seq = (const float*)d_in[3];
  const int*   k_len = (const int*)d_in[4];
  const float* k_R   = (const float*)d_in[5];
  const float* c1w   = (const float*)d_in[6];
  const float* c1b   = (const float*)d_in[7];
  const float* c2w   = (const float*)d_in[8];
  const float* c2b   = (const float*)d_in[9];
  const float* c3w   = (const float*)d_in[10];
  const float* c3b   = (const float*)d_in[11];
  float* out = (float*)d_out;
  float* out_dis = out + (size_t)NB * TT * TT;

  char* base = (char*)d_ws;
  size_t off = 0;
  auto take = [&](size_t bytes)->char*{
    char* p = base + off;
    off = (off + bytes + 255) & ~(size_t)255;
    return p;
  };
  float* Dbuf   = (float*)take((size_t)NB * TT * TT * 4);
  float* qq     = (float*)take((size_t)NB * TT * 4);
  float* kkn    = (float*)take((size_t)NB * TT * 4);
  u32*   inb    = (u32*)  take((size_t)NB * TT * TT * 4);
  u8*    w2p    = (u8*)   take(25 * 1024);
  u16*   w1c    = (u16*)  take(5 * 1024);
  u16*   qb16   = (u16*)  take((size_t)NB * TT * DK * 2);
  u16*   kb16   = (u16*)  take((size_t)NB * TT * DK * 2);
  size_t fixed = off;
  int BCH = 64;
  while (BCH > 1 && fixed + (size_t)BCH * TT * TT * 32 + 1024 > ws_size) BCH >>= 1;
  u8* act2 = (u8*)take((size_t)BCH * TT * TT * 32);

  row_norms_k<<<4123, 256, 0, stream>>>(q_seq, k_seq, qq, kkn, qb16, kb16, c2w, c1w, w2p, w1c, out_dis);
  cdist_mfma_k<<<256, 256, 0, stream>>>(qb16, kb16, qq, kkn, q_len, k_len, q_R, k_R, Dbuf, inb);
  for (int b0 = 0; b0 < NB; b0 += BCH){
    int nb = BCH;
    conv12_mfma_k<<<dim3(16, nb), 512, 0, stream>>>(inb + (size_t)b0 * TT * TT, w2p, w1c, c1b, c2b, act2);
    conv3sm_k<<<dim3(64, nb), 512, 0, stream>>>(act2, c3w, c3b, Dbuf, q_len, k_len, out, out_dis, b0);
  }
}

// Round 25
// 93.466 us; speedup vs baseline: 2.1003x; 1.4591x over previous
//
#include <hip/hip_runtime.h>
#include <hip/hip_bf16.h>
#include <stdint.h>

using u16 = unsigned short;
using u32 = unsigned int;
using u8  = unsigned char;

#define NB 64
#define TT 128
#define DK 768
#define MC 30

typedef float f32x16 __attribute__((ext_vector_type(16)));
typedef __bf16 bf16x8 __attribute__((ext_vector_type(8)));
typedef long long ll;
typedef __attribute__((ext_vector_type(2))) ll ll2;
#if __has_builtin(__builtin_amdgcn_mfma_scale_f32_32x32x64_f8f6f4)
#define HAVE_MXFP8 1
typedef int i32x8 __attribute__((ext_vector_type(8)));
#endif
#if __has_builtin(__builtin_amdgcn_global_load_lds)
#define HAVE_GLDS 1
#endif

__device__ inline void unpack2(u32 u, float& lo, float& hi){
  union{u32 i; float f;} a, b; a.i = u << 16; b.i = u & 0xFFFF0000u; lo = a.f; hi = b.f;
}
__device__ inline u16 f2bf(float f){
  union{u32 i; float f;} v; v.f = f;
  u32 r = v.i + 0x7FFFu + ((v.i >> 16) & 1u);
  return (u16)(r >> 16);
}
__device__ inline u32 pack2bf(float a, float b){ return (u32)f2bf(a) | ((u32)f2bf(b) << 16); }

// ---------------- fp8 e4m3fn pack/unpack helpers ----------------
#if __has_builtin(__builtin_amdgcn_cvt_pk_fp8_f32)
template<bool HIW>
__device__ inline u32 pk_fp8(float a, float b, u32 old){
  return (u32)__builtin_amdgcn_cvt_pk_fp8_f32(a, b, (int)old, HIW);
}
#else
__device__ inline u8 f2fp8_1(float f){
  union{float f; u32 u;} v; v.f = f;
  u32 s = (v.u >> 24) & 0x80u;
  u32 abs = v.u & 0x7fffffffu;
  if (abs < 0x3c800000u){
    float sc = fabsf(f) * 512.0f;
    int m = (int)rintf(sc);
    return (u8)(s | (u32)m);
  }
  u32 e8 = abs >> 23; u32 mant = abs & 0x7fffffu;
  u32 m3 = mant >> 20; u32 rest = mant & 0xfffffu;
  u32 rb = (rest > 0x80000u) || (rest == 0x80000u && (m3 & 1u));
  m3 += rb;
  u32 E = e8 - 120u;
  if (m3 == 8u){ m3 = 0u; E += 1u; }
  if (E >= 16u || (E == 15u && m3 == 7u)) return (u8)(s | 0x7Eu);
  return (u8)(s | (E << 3) | m3);
}
template<bool HIW>
__device__ inline u32 pk_fp8(float a, float b, u32 old){
  u32 w = (u32)f2fp8_1(a) | ((u32)f2fp8_1(b) << 8);
  return HIW ? ((old & 0x0000FFFFu) | (w << 16)) : ((old & 0xFFFF0000u) | w);
}
#endif

#if __has_builtin(__builtin_amdgcn_cvt_pk_f32_fp8)
__device__ inline void upk_fp8x4(u32 w, float* x){
  auto a0 = __builtin_amdgcn_cvt_pk_f32_fp8((int)w, false);
  auto a1 = __builtin_amdgcn_cvt_pk_f32_fp8((int)w, true);
  x[0] = a0[0]; x[1] = a0[1]; x[2] = a1[0]; x[3] = a1[1];
}
#else
__device__ inline float fp8_1(u32 byte){
  u32 s = (byte & 0x80u) << 24;
  u32 E = (byte >> 3) & 15u, M = byte & 7u;
  union{u32 u; float f;} v;
  if (E == 0){ v.f = (float)M * (1.0f/512.0f); v.u |= s; }
  else v.u = s | ((E + 120u) << 23) | (M << 20);
  return v.f;
}
__device__ inline void upk_fp8x4(u32 w, float* x){
  x[0] = fp8_1(w & 255u); x[1] = fp8_1((w >> 8) & 255u);
  x[2] = fp8_1((w >> 16) & 255u); x[3] = fp8_1(w >> 24);
}
#endif

// ic PERMUTATION (applied identically to w2p, c2in, act2, conv3 weights):
// channel c = 8q + 4h + j  lives at byte p = h*16 + q*4 + j   (q,j in 0..3, h in 0..1)

// ---------------- kernel 1: row norms + bf16 conversion (PRE-SWIZZLED output)
//                  + fused weight prep (blocks >= 4096) ----------------
__global__ __launch_bounds__(256) void row_norms_k(const float* __restrict__ q, const float* __restrict__ k,
    float* __restrict__ qq, float* __restrict__ kk,
    u16* __restrict__ qb16, u16* __restrict__ kb16,
    const float* __restrict__ w2, const float* __restrict__ w1,
    u8* __restrict__ w2p, u16* __restrict__ w1c){
  if (blockIdx.x >= 4096){
    int bidx = blockIdx.x - 4096;
    if (bidx < 25){
      int tap = bidx;
      int i = threadIdx.x;
      int oc = i >> 3, qd = i & 7;
      int ic0 = 8*(qd & 3) + 4*(qd >> 2);   // permuted: byte qd*4 holds channels ic0..ic0+3
      float v[4];
      #pragma unroll
      for (int j = 0; j < 4; ++j)
        v[j] = (oc < MC && ic0 + j < MC) ? w2[(oc*MC + ic0 + j)*25 + tap] : 0.f;
      u32 w = pk_fp8<false>(v[0], v[1], 0u);
      w = pk_fp8<true>(v[2], v[3], w);
      int lo = ((oc << 5) + (qd << 2)) ^ ((oc & 7) << 4);
      *(u32*)(w2p + tap*1024 + lo) = w;
    } else {
      for (int i = threadIdx.x; i < 2560; i += 256){
        int dy = i >> 9; int rem = i & 511; int oc = rem >> 4; int kx = rem & 15;
        int dx = kx >> 1, c = kx & 1;
        float v = (oc < MC && dx < 5) ? w1[(oc*2 + c)*25 + dy*5 + dx] : 0.f;
        int byteoff = dy*1024 + (((oc<<5) + (kx<<1)) ^ ((oc&7)<<4));
        *(u16*)((char*)w1c + byteoff) = f2bf(v);
      }
    }
    return;
  }
  int wave = blockIdx.x * 4 + (threadIdx.x >> 6);
  int lane = threadIdx.x & 63;
  const float* src; float* dst; u16* bdst; int row;
  if (wave < NB * TT) { src = q; dst = qq; bdst = qb16; row = wave; }
  else                { src = k; dst = kk; bdst = kb16; row = wave - NB * TT; }
  const float4* p = (const float4*)(src + (size_t)row * DK);
  char* ob = (char*)(bdst + (size_t)row * DK);
  int key = (row & 7) << 4;
  float s = 0.f;
  {
    float4 a = p[2*lane], b2 = p[2*lane + 1];
    s += a.x*a.x + a.y*a.y + a.z*a.z + a.w*a.w;
    s += b2.x*b2.x + b2.y*b2.y + b2.z*b2.z + b2.w*b2.w;
    uint4 st;
    st.x = pack2bf(a.x, a.y);  st.y = pack2bf(a.z, a.w);
    st.z = pack2bf(b2.x, b2.y); st.w = pack2bf(b2.z, b2.w);
    *(uint4*)(ob + ((lane << 4) ^ key)) = st;
  }
  if (lane < 32){
    int g = 64 + lane;
    float4 a = p[2*g], b2 = p[2*g + 1];
    s += a.x*a.x + a.y*a.y + a.z*a.z + a.w*a.w;
    s += b2.x*b2.x + b2.y*b2.y + b2.z*b2.z + b2.w*b2.w;
    uint4 st;
    st.x = pack2bf(a.x, a.y);  st.y = pack2bf(a.z, a.w);
    st.z = pack2bf(b2.x, b2.y); st.w = pack2bf(b2.z, b2.w);
    *(uint4*)(ob + ((g << 4) ^ key)) = st;
  }
  #pragma unroll
  for (int o = 32; o; o >>= 1) s += __shfl_xor(s, o);
  if (lane == 0) dst[row] = s;
}

// ---------------- kernel 2: cdist via bf16 MFMA, async linear staging, XCD-grouped grid ----------------
__global__ __launch_bounds__(256) void cdist_mfma_k(
    const u16* __restrict__ Qb16, const u16* __restrict__ Kb16,
    const float* __restrict__ qq, const float* __restrict__ kk,
    const int* __restrict__ qlen, const int* __restrict__ klen,
    const float* __restrict__ qR, const float* __restrict__ kR,
    float* __restrict__ Dout, u32* __restrict__ inb){
  __shared__ __align__(16) char qs[32 * 1536];
  __shared__ __align__(16) char ksm[128 * 256];
  int bid = blockIdx.x;
  int b  = ((bid & 7) << 3) + (bid >> 5);
  int rt = (bid >> 3) & 3;
  int r0 = rt * 32;
  int tid = threadIdx.x;
  int lane = tid & 63, w = tid >> 6;
  int hi = lane >> 5, l31 = lane & 31;
  const char* Qg = (const char*)(Qb16 + ((size_t)b * TT + r0) * DK);
  const char* Kg = (const char*)(Kb16 + (size_t)b * TT * DK);
#ifdef HAVE_GLDS
  #pragma unroll
  for (int i = 0; i < 12; ++i){
    int gb = (i*4 + w) << 6;
    __builtin_amdgcn_global_load_lds((const u32*)(Qg + ((gb + lane) << 4)),
                                     (u32*)(qs + (gb << 4)), 16, 0, 0);
  }
#else
  for (int idx = tid; idx < 3072; idx += 256)
    *(uint4*)(qs + idx*16) = *(const uint4*)(Qg + idx*16);
#endif
  int col = w * 32 + l31;
  f32x16 acc;
  #pragma unroll
  for (int r = 0; r < 16; ++r) acc[r] = 0.f;
  for (int kc = 0; kc < DK; kc += 128){
    __syncthreads();
#ifdef HAVE_GLDS
    const char* Ks = Kg + kc*2;
    #pragma unroll
    for (int i = 0; i < 8; ++i){
      int gb = (i*4 + w) << 6;
      int g = gb + lane;
      __builtin_amdgcn_global_load_lds((const u32*)(Ks + (g >> 4)*1536 + ((g & 15) << 4)),
                                       (u32*)(ksm + (gb << 4)), 16, 0, 0);
    }
#else
    for (int idx = tid; idx < 2048; idx += 256){
      int c = idx >> 4, j = idx & 15;
      *(uint4*)(ksm + idx*16) = *(const uint4*)(Kg + c*1536 + kc*2 + j*16);
    }
#endif
    __syncthreads();
    #pragma unroll
    for (int k8 = 0; k8 < 8; ++k8){
      bf16x8 a  = *(const bf16x8*)(qs  + l31 * 1536 + (((kc + k8*16 + hi*8) * 2) ^ ((l31 & 7) << 4)));
      bf16x8 bv = *(const bf16x8*)(ksm + col * 256  + (((k8*16 + hi*8) * 2) ^ ((col & 7) << 4)));
      acc = __builtin_amdgcn_mfma_f32_32x32x16_bf16(a, bv, acc, 0, 0, 0);
    }
  }
  int ql = qlen[b], kl = klen[b];
  float kkv = kk[b * TT + col];
  float krv = kR[b * TT + col];
  bool cm = col < kl;
  #pragma unroll
  for (int r = 0; r < 16; ++r){
    int row = r0 + (r & 3) + 8 * (r >> 2) + 4 * hi;
    float qqv = qq[b * TT + row];
    float sq = qqv + kkv - 2.f * acc[r];
    float d = sqrtf(fmaxf(sq, 1e-12f));
    bool m = (row < ql) && cm;
    float dm = m ? d : 0.f;
    float pm = m ? fabsf(qR[b * TT + row] - krv) : 0.f;
    Dout[(((size_t)b * TT + row) << 7) + col] = dm;
    inb[(((size_t)b * TT + row) << 7) + col] = pack2bf(dm, pm);
  }
}

// ---------------- fused conv1+conv2 (permuted-ic contiguous stores) ----------------
#define C1_ROWW 136
#define C2_IN_ROWB 4224                 // 132 px * 32 B
#define F_INB_BYTES (16*C1_ROWW*4)      // 8704
#define F_C2_OFF F_INB_BYTES
#define F_SMEM (F_INB_BYTES + 12*C2_IN_ROWB)   // 59392

__global__ __launch_bounds__(512, 4) void conv12_mfma_k(
    const u32* __restrict__ inb, const u8* __restrict__ w2p, const u16* __restrict__ w1c,
    const float* __restrict__ b1, const float* __restrict__ b2, u8* __restrict__ act2){
  __shared__ __align__(16) char smem[F_SMEM];
  u32* ilds = (u32*)smem;
  char* c2in = smem + F_C2_OFF;
  int o  = blockIdx.x;
  int yg = ((o & 7) << 1) + (o >> 3);
  int bb = blockIdx.y;
  int y0 = yg * 8;
  int tid = threadIdx.x;
  for (int i = tid; i < 16*C1_ROWW; i += 512){
    int r = i / C1_ROWW, xi = i - r * C1_ROWW;
    int gy = y0 - 4 + r, gx = xi - 2;
    u32 v = 0;
    if ((unsigned)gy < 128u && (unsigned)gx < 128u)
      v = inb[(((size_t)bb * 128 + gy) << 7) + gx];
    ilds[r * C1_ROWW + xi] = v;
  }
  for (int i = tid; i < 96; i += 512){
    int r = i >> 3; int rem = i & 7; int ci = rem >> 1; int h = rem & 1;
    int lx = (ci < 2) ? ci : (128 + ci);
    int addr = r*C2_IN_ROWB + (((lx << 5) + (h << 4)) ^ ((lx & 7) << 4));
    *(uint4*)(c2in + addr) = make_uint4(0,0,0,0);
  }
  int lane = tid & 63, w = tid >> 6;
  int hi = lane >> 5, l31 = lane & 31;
  int aSwz = ((l31 << 5) + (hi << 4)) ^ ((l31 & 7) << 4);
  bf16x8 afr[5];
  #pragma unroll
  for (int dy = 0; dy < 5; ++dy)
    afr[dy] = *(const bf16x8*)((const char*)w1c + dy*1024 + aSwz);
  float b1v[16];
  #pragma unroll
  for (int r = 0; r < 16; ++r){
    int oc = (r & 3) + 8*(r >> 2) + 4*hi;
    b1v[r] = (oc < MC) ? b1[oc] : 0.f;
  }
  __syncthreads();
  // ---- conv1 phase: 1 contiguous uint4 store per (lane, tile)
  for (int rep = 0; rep < 2; ++rep){
    if (rep == 1 && w >= 4) break;
    int idx = (rep == 0) ? w : (8 + w);
    int gy = y0 - 2 + idx;
    bool oob = (unsigned)gy >= 128u;
    #pragma unroll
    for (int t = 0; t < 4; ++t){
      int px = t*32 + l31;
      uint4 st = make_uint4(0,0,0,0);
      if (!oob){
        f32x16 acc;
        #pragma unroll
        for (int r = 0; r < 16; ++r) acc[r] = 0.f;
        #pragma unroll
        for (int dy = 0; dy < 5; ++dy){
          const u32* rp = &ilds[(idx + dy)*C1_ROWW + px + hi*4];
          union { u32 uw[4]; bf16x8 v; } ub;
          ub.uw[0] = rp[0]; ub.uw[1] = rp[1]; ub.uw[2] = rp[2]; ub.uw[3] = rp[3];
          acc = __builtin_amdgcn_mfma_f32_32x32x16_bf16(afr[dy], ub.v, acc, 0, 0, 0);
        }
        u32 wd[4];
        #pragma unroll
        for (int qd = 0; qd < 4; ++qd){
          u32 word = pk_fp8<false>(fmaxf(acc[4*qd+0]+b1v[4*qd+0], 0.f),
                                   fmaxf(acc[4*qd+1]+b1v[4*qd+1], 0.f), 0u);
          word = pk_fp8<true>(fmaxf(acc[4*qd+2]+b1v[4*qd+2], 0.f),
                              fmaxf(acc[4*qd+3]+b1v[4*qd+3], 0.f), word);
          wd[qd] = word;
        }
        st.x = wd[0]; st.y = wd[1]; st.z = wd[2]; st.w = wd[3];
      }
      int lx = px + 2;
      int addr = idx*C2_IN_ROWB + (((lx << 5) + (hi << 4)) ^ ((lx & 7) << 4));
      *(uint4*)(c2in + addr) = st;
    }
  }
  __syncthreads();
  // ---- conv2 phase (MX-scaled fp8, K=64, unit scales), A-frags from global
  f32x16 acc[4];
  #pragma unroll
  for (int t = 0; t < 4; ++t)
    #pragma unroll
    for (int r = 0; r < 16; ++r) acc[t][r] = 0.f;
  #pragma unroll
  for (int dy = 0; dy < 5; ++dy){
    const char* rowp = c2in + (w + dy)*C2_IN_ROWB;
    ll2 aw[5];
    #pragma unroll
    for (int dx = 0; dx < 5; ++dx)
      aw[dx] = *(const ll2*)(w2p + (dy*5 + dx)*1024 + aSwz);
#ifdef HAVE_MXFP8
    union U8x { struct { ll2 lo, hi; } p; i32x8 v; };
    U8x a01, a23, a4z;
    ll2 zz; zz.x = 0; zz.y = 0;
    a01.p.lo = aw[0]; a01.p.hi = aw[1];
    a23.p.lo = aw[2]; a23.p.hi = aw[3];
    a4z.p.lo = aw[4]; a4z.p.hi = zz;
    #pragma unroll
    for (int t = 0; t < 4; ++t){
      int pxb = t*32 + l31;
      ll2 bl[5];
      #pragma unroll
      for (int dx = 0; dx < 5; ++dx){
        int px2 = pxb + dx;
        int boff = ((px2 << 5) + (hi << 4)) ^ ((px2 & 7) << 4);
        bl[dx] = *(const ll2*)(rowp + boff);
      }
      U8x b01, b23, b4d;
      b01.p.lo = bl[0]; b01.p.hi = bl[1];
      b23.p.lo = bl[2]; b23.p.hi = bl[3];
      b4d.p.lo = bl[4]; b4d.p.hi = bl[4];
      acc[t] = __builtin_amdgcn_mfma_scale_f32_32x32x64_f8f6f4(
                 a01.v, b01.v, acc[t], 0, 0, 0, 0x7F7F7F7F, 0, 0x7F7F7F7F);
      acc[t] = __builtin_amdgcn_mfma_scale_f32_32x32x64_f8f6f4(
                 a23.v, b23.v, acc[t], 0, 0, 0, 0x7F7F7F7F, 0, 0x7F7F7F7F);
      acc[t] = __builtin_amdgcn_mfma_scale_f32_32x32x64_f8f6f4(
                 a4z.v, b4d.v, acc[t], 0, 0, 0, 0x7F7F7F7F, 0, 0x7F7F7F7F);
    }
#else
    #pragma unroll
    for (int dx = 0; dx < 5; ++dx){
      ll2 a = aw[dx];
      #pragma unroll
      for (int t = 0; t < 4; ++t){
        int px2 = t*32 + l31 + dx;
        int boff = ((px2 << 5) + (hi << 4)) ^ ((px2 & 7) << 4);
        ll2 b = *(const ll2*)(rowp + boff);
        acc[t] = __builtin_amdgcn_mfma_f32_32x32x16_fp8_fp8(a.x, b.x, acc[t], 0, 0, 0);
        acc[t] = __builtin_amdgcn_mfma_f32_32x32x16_fp8_fp8(a.y, b.y, acc[t], 0, 0, 0);
      }
    }
#endif
  }
  float b2v[16];
  #pragma unroll
  for (int r = 0; r < 16; ++r){
    int oc = (r & 3) + 8*(r >> 2) + 4*hi;
    b2v[r] = (oc < MC) ? b2[oc] : 0.f;
  }
  __syncthreads();
  int wbase = w * 4096;
  #pragma unroll
  for (int t = 0; t < 4; ++t){
    int px = t*32 + l31;
    u32 wd[4];
    #pragma unroll
    for (int qd = 0; qd < 4; ++qd){
      float v0 = fmaxf(acc[t][4*qd+0] + b2v[4*qd+0], 0.f);
      float v1 = fmaxf(acc[t][4*qd+1] + b2v[4*qd+1], 0.f);
      float v2 = fmaxf(acc[t][4*qd+2] + b2v[4*qd+2], 0.f);
      float v3 = fmaxf(acc[t][4*qd+3] + b2v[4*qd+3], 0.f);
      u32 word = pk_fp8<false>(v0, v1, 0u);
      word = pk_fp8<true>(v2, v3, word);
      wd[qd] = word;
    }
    uint4 st; st.x = wd[0]; st.y = wd[1]; st.z = wd[2]; st.w = wd[3];
    int addr = wbase + (((px << 5) + (hi << 4)) ^ ((px & 7) << 4));
    *(uint4*)(c2in + addr) = st;
  }
  int y = y0 + w;
  #pragma unroll
  for (int p = 0; p < 8; ++p){
    int x = p*16 + (lane >> 2), cg = lane & 3;
    int addr = wbase + (((x << 5) + (cg << 3)) ^ ((x & 7) << 4));
    uint2 v = *(const uint2*)(c2in + addr);
    *(uint2*)(act2 + ((((size_t)bb*128 + y)*128 + x) << 5) + cg*8) = v;
  }
}

// ---------------- conv3 + mask + row softmax + A write + row D*A ----------------
__global__ __launch_bounds__(512) void conv3sm_k(const u8* __restrict__ act2,
    const float* __restrict__ w3, const float* __restrict__ b3, const float* __restrict__ Dbuf,
    const int* __restrict__ qlen, const int* __restrict__ klen,
    float* __restrict__ Aout, float* __restrict__ rowsum, int b0){
  __shared__ float wlds[9][32];
  __shared__ float ex0[512], ex2[512];
  __shared__ float redm[8], reds[8], redd[8];
  int o  = blockIdx.x;                    // 0..63
  int ip = ((o & 7) << 3) + (o >> 3);     // XCD-chunked row-pair index
  int bb = blockIdx.y;
  int b  = b0 + bb;
  int tid = threadIdx.x;
  for (int idx = tid; idx < 288; idx += 512){
    int tap = idx >> 5, p = idx & 31;
    int cp = 8*((p >> 2) & 3) + 4*(p >> 4) + (p & 3);   // channel stored at byte p
    wlds[tap][p] = (cp < MC) ? w3[cp * 9 + tap] : 0.f;
  }
  __syncthreads();
  int r  = tid >> 8;
  int t  = tid & 255;
  int px = t >> 1, half = t & 1;
  int i  = ip * 2 + r;
  int wv = tid >> 6;
  float T0 = 0.f, T1 = 0.f, T2 = 0.f;
  #pragma unroll
  for (int dy = 0; dy < 3; ++dy){
    int gy = i - 1 + dy;
    uint4 v = make_uint4(0, 0, 0, 0);
    if ((unsigned)gy < 128u)
      v = *(const uint4*)(act2 + ((((size_t)bb*128 + gy)*128 + px) << 5) + half*16);
    float x[16];
    upk_fp8x4(v.x, x); upk_fp8x4(v.y, x + 4);
    upk_fp8x4(v.z, x + 8); upk_fp8x4(v.w, x + 12);
    const float* w0p = &wlds[dy*3 + 0][half*16];
    const float* w1p = &wlds[dy*3 + 1][half*16];
    const float* w2q = &wlds[dy*3 + 2][half*16];
    #pragma unroll
    for (int c = 0; c < 16; ++c){
      T0 = fmaf(x[c], w0p[c], T0);
      T1 = fmaf(x[c], w1p[c], T1);
      T2 = fmaf(x[c], w2q[c], T2);
    }
  }
  ex0[tid] = T0; ex2[tid] = T2;
  __syncthreads();
  float acc = T1;
  if (px > 0)   acc += ex0[tid - 2];
  if (px < 127) acc += ex2[tid + 2];
  acc += __shfl_xor(acc, 1);
  acc += b3[0];
  float Dv = Dbuf[(((size_t)b * 128 + i) << 7) + px];
  bool m = (i < qlen[b]) && (px < klen[b]);
  float xv = m ? -(acc + Dv) : -100.f;
  float mx = xv;
  #pragma unroll
  for (int o2 = 32; o2; o2 >>= 1) mx = fmaxf(mx, __shfl_xor(mx, o2));
  if ((tid & 63) == 0) redm[wv] = mx;
  __syncthreads();
  int rb4 = r << 2;
  mx = fmaxf(fmaxf(redm[rb4], redm[rb4+1]), fmaxf(redm[rb4+2], redm[rb4+3]));
  float e = __expf(xv - mx);
  float s  = e;
  float de = Dv * e;
  #pragma unroll
  for (int o2 = 32; o2; o2 >>= 1){ s += __shfl_xor(s, o2); de += __shfl_xor(de, o2); }
  if ((tid & 63) == 0){ reds[wv] = s; redd[wv] = de; }
  __syncthreads();
  float s4 = (reds[rb4] + reds[rb4+1]) + (reds[rb4+2] + reds[rb4+3]);
  float a = e * 2.0f / s4;
  if (half == 0) Aout[(((size_t)b * 128 + i) << 7) + px] = a;
  if (t == 0){
    float d4 = (redd[rb4] + redd[rb4+1]) + (redd[rb4+2] + redd[rb4+3]);
    rowsum[b * TT + i] = d4 / s4;
  }
}

// ---------------- dis reduce ----------------
__global__ __launch_bounds__(128) void dis_k(const float* __restrict__ rowsum, float* __restrict__ out){
  int b = blockIdx.x, tid = threadIdx.x;
  float v = rowsum[b * TT + tid];
  #pragma unroll
  for (int o = 32; o; o >>= 1) v += __shfl_xor(v, o);
  __shared__ float red[2];
  if ((tid & 63) == 0) red[tid >> 6] = v;
  __syncthreads();
  if (tid == 0) out[b] = (red[0] + red[1]) * (1.0f / 128.0f);
}

extern "C" void kernel_launch(void* const* d_in, const int* in_sizes, int n_in,
                              void* d_out, int out_size, void* d_ws, size_t ws_size,
                              hipStream_t stream){
  const float* q_seq = (const float*)d_in[0];
  const int*   q_len = (const int*)d_in[1];
  const float* q_R   = (const float*)d_in[2];
  const float* k_seq = (const float*)d_in[3];
  const int*   k_len = (const int*)d_in[4];
  const float* k_R   = (const float*)d_in[5];
  const float* c1w   = (const float*)d_in[6];
  const float* c1b   = (const float*)d_in[7];
  const float* c2w   = (const float*)d_in[8];
  const float* c2b   = (const float*)d_in[9];
  const float* c3w   = (const float*)d_in[10];
  const float* c3b   = (const float*)d_in[11];
  float* out = (float*)d_out;

  char* base = (char*)d_ws;
  size_t off = 0;
  auto take = [&](size_t bytes)->char*{
    char* p = base + off;
    off = (off + bytes + 255) & ~(size_t)255;
    return p;
  };
  float* Dbuf   = (float*)take((size_t)NB * TT * TT * 4);
  float* qq     = (float*)take((size_t)NB * TT * 4);
  float* kkn    = (float*)take((size_t)NB * TT * 4);
  float* rowsum = (float*)take((size_t)NB * TT * 4);
  u32*   inb    = (u32*)  take((size_t)NB * TT * TT * 4);
  u8*    w2p    = (u8*)   take(25 * 1024);
  u16*   w1c    = (u16*)  take(5 * 1024);
  u16*   qb16   = (u16*)  take((size_t)NB * TT * DK * 2);
  u16*   kb16   = (u16*)  take((size_t)NB * TT * DK * 2);
  size_t fixed = off;
  int BCH = 64;
  while (BCH > 1 && fixed + (size_t)BCH * TT * TT * 32 + 1024 > ws_size) BCH >>= 1;
  u8* act2 = (u8*)take((size_t)BCH * TT * TT * 32);

  row_norms_k<<<4122, 256, 0, stream>>>(q_seq, k_seq, qq, kkn, qb16, kb16, c2w, c1w, w2p, w1c);
  cdist_mfma_k<<<256, 256, 0, stream>>>(qb16, kb16, qq, kkn, q_len, k_len, q_R, k_R, Dbuf, inb);
  for (int b0 = 0; b0 < NB; b0 += BCH){
    int nb = BCH;
    conv12_mfma_k<<<dim3(16, nb), 512, 0, stream>>>(inb + (size_t)b0 * TT * TT, w2p, w1c, c1b, c2b, act2);
    conv3sm_k<<<dim3(64, nb), 512, 0, stream>>>(act2, c3w, c3b, Dbuf, q_len, k_len, out, rowsum, b0);
  }
  dis_k<<<NB, 128, 0, stream>>>(rowsum, out + (size_t)NB * TT * TT);
}